// Round 8
// baseline (173.317 us; speedup 1.0000x reference)
//
#include <hip/hip_runtime.h>
#include <hip/hip_bf16.h>

// CQAttention B=32 D=128 Lc=2048 Lq=256 — bf16 MFMA, P-materialized pipeline v4.
//
// vs v3 (round 7):
//  k1: Praw writes deferred to registers (one burst at kernel end — removes the
//      per-tile vmcnt(0)-drain before each barrier); E double-buffered so the
//      main loop has ONE barrier per c-tile instead of two.
//  k2: P tile (64c x 256q, 32KB) staged once into XOR-swizzled LDS with
//      coalesced uint4 loads; B-frags + l1 rowsums read LDS (no duplicate
//      global P reads, no dependent global load under every MFMA). Epilogue
//      via LDS transpose (aliases dead P buffer): all C reads and out writes
//      are f32x4, 256B-contiguous rows.
// Same verified math/masks as rounds 5-7. Tiers: full-batch (ws>=74MB) /
// two-half (ws>=39.5MB, proven budget) / fp32 fallback.

typedef unsigned short u16;
typedef short bf16x8 __attribute__((ext_vector_type(8)));
typedef float f32x4 __attribute__((ext_vector_type(4)));

#define MFMA16(a, b, c) __builtin_amdgcn_mfma_f32_16x16x32_bf16(a, b, c, 0, 0, 0)

__device__ __forceinline__ unsigned pack_bf16(float a, float b) {
  __hip_bfloat16 ha = __float2bfloat16(a), hb = __float2bfloat16(b);
  unsigned short ua = __builtin_bit_cast(unsigned short, ha);
  unsigned short ub = __builtin_bit_cast(unsigned short, hb);
  return (unsigned)ua | ((unsigned)ub << 16);
}
__device__ __forceinline__ u16 bf16u(float a) {
  __hip_bfloat16 h = __float2bfloat16(a);
  return __builtin_bit_cast(unsigned short, h);
}
__device__ __forceinline__ float bf2f(unsigned x) {
  unsigned v = x << 16;
  return __builtin_bit_cast(float, v);
}

// ------------------------ prepC: per pass, 512 thr --------------------------
__global__ void __launch_bounds__(512) prepC(const float* __restrict__ C,
                                             const int* __restrict__ Cmask,
                                             const float* __restrict__ w4C,
                                             const float* __restrict__ bias,
                                             u16* __restrict__ Ctb,
                                             u16* __restrict__ Cdb,
                                             float* __restrict__ s0r,
                                             float* __restrict__ s0m,
                                             int b0, int lg) {
  __shared__ float wL[128];
  __shared__ float red[512];
  const int t = threadIdx.x;
  const int c_loc = t & 255, dh = t >> 8;
  const int b_loc = blockIdx.x & ((1 << lg) - 1), ct = blockIdx.x >> lg;
  const int b = b0 + b_loc;
  const int c = ct * 256 + c_loc;
  if (t < 128) wL[t] = w4C[t];
  __syncthreads();
  const float* src = C + (size_t)b * (128 * 2048) + c;
  u16* dstT = Ctb + ((size_t)(b_loc * 2048 + c)) * 128;
  u16* dstD = Cdb + (size_t)b_loc * (128 * 2048) + c;
  float s = 0.f;
#pragma unroll
  for (int dg = 0; dg < 8; ++dg) {
    const int d0 = dh * 64 + dg * 8;
    float v[8];
#pragma unroll
    for (int i = 0; i < 8; ++i) v[i] = src[(size_t)(d0 + i) * 2048];
#pragma unroll
    for (int i = 0; i < 8; ++i) s += v[i] * wL[d0 + i];
    uint4 o = {pack_bf16(v[0], v[1]), pack_bf16(v[2], v[3]),
               pack_bf16(v[4], v[5]), pack_bf16(v[6], v[7])};
    *(uint4*)(dstT + d0) = o;
    const u16* ou = (const u16*)&o;
#pragma unroll
    for (int i = 0; i < 8; ++i) dstD[(size_t)(d0 + i) * 2048] = ou[i];
  }
  red[t] = s;
  __syncthreads();
  if (t < 256) {
    const int idx = b * 2048 + ct * 256 + t;
    const float tot = red[t] + red[t + 256] + bias[0];
    s0r[idx] = tot;
    s0m[idx] = Cmask[idx] ? tot : -1e30f;
  }
}

// --------------------------- prepQ: all b, once -----------------------------
__global__ void __launch_bounds__(512) prepQ(const float* __restrict__ Q,
                                             const int* __restrict__ Qmask,
                                             const float* __restrict__ w4Q,
                                             const float* __restrict__ w4mlu,
                                             u16* __restrict__ Qwb,
                                             u16* __restrict__ Qdb,
                                             float* __restrict__ s1r,
                                             float* __restrict__ s1m) {
  __shared__ float wqL[128], wmL[128];
  __shared__ float red[512];
  const int t = threadIdx.x;
  const int q = t & 255, dh = t >> 8;
  const int b = blockIdx.x;
  if (t < 128) { wqL[t] = w4Q[t]; wmL[t] = w4mlu[t]; }
  __syncthreads();
  const float* src = Q + (size_t)b * (128 * 256) + q;
  u16* dstW = Qwb + ((size_t)(b * 256 + q)) * 128;
  u16* dstD = Qdb + (size_t)b * (128 * 256) + q;
  float s = 0.f;
#pragma unroll
  for (int dg = 0; dg < 8; ++dg) {
    const int d0 = dh * 64 + dg * 8;
    float v[8];
#pragma unroll
    for (int i = 0; i < 8; ++i) v[i] = src[(d0 + i) * 256];
#pragma unroll
    for (int i = 0; i < 8; ++i) s += v[i] * wqL[d0 + i];
#pragma unroll
    for (int i = 0; i < 8; ++i) dstD[(d0 + i) * 256] = bf16u(v[i]);
    float wv[8];
#pragma unroll
    for (int i = 0; i < 8; ++i) wv[i] = v[i] * wmL[d0 + i];
    uint4 o = {pack_bf16(wv[0], wv[1]), pack_bf16(wv[2], wv[3]),
               pack_bf16(wv[4], wv[5]), pack_bf16(wv[6], wv[7])};
    *(uint4*)(dstW + d0) = o;
  }
  red[t] = s;
  __syncthreads();
  if (t < 256) {
    const int idx = b * 256 + t;
    const float tot = red[t] + red[t + 256];
    s1r[idx] = tot;
    s1m[idx] = Qmask[idx] ? tot : -1e30f;
  }
}

// ------------------------- k1: S, P, T, l2 (per pass) ------------------------
// grid nb*16; 512 thr (8 waves). E double-buffered; Praw deferred in regs.
__global__ void __launch_bounds__(512) k1(
    const u16* __restrict__ Ctb, const u16* __restrict__ Cdb,
    const u16* __restrict__ Qwb, const float* __restrict__ s0r,
    const float* __restrict__ s0m, const float* __restrict__ s1r,
    const float* __restrict__ s1m, u16* __restrict__ Tdq,
    u16* __restrict__ Praw, int b0, int lg) {
  __shared__ __align__(16) char E[2][16 * 512];
  __shared__ float l2red[128];
  __shared__ float l2L[16];

  const int tid = threadIdx.x, w = tid >> 6, l = tid & 63;
  const int qt = l >> 4, ln = l & 15;
  const int p = blockIdx.x;
  const int b_loc = p & ((1 << lg) - 1);  // same b_loc -> same XCD (mod 8)
  const int q0g = (p >> lg) << 4;
  const int b = b0 + b_loc;

  // Qw B-frags: B[k=d][n=q], lane ln = q
  bf16x8 qwB[4];
  {
    const u16* Qwp = Qwb + ((size_t)(b * 256 + q0g + ln)) * 128;
#pragma unroll
    for (int kk = 0; kk < 4; ++kk) qwB[kk] = *(const bf16x8*)(Qwp + kk * 32 + qt * 8);
  }
  const float s1v = s1r[b * 256 + q0g + ln];
  const bool qm = s1m[b * 256 + q0g + ln] > -1e29f;

  f32x4 accT = {};     // T[q = qt*4+r][d = w*16+ln]
  float l2a = 0.f;
  uint2 eqp[8][2];     // deferred Praw values (qmask'd), packed bf16

#pragma unroll
  for (int ci = 0; ci < 8; ++ci) {
    const int cg = ci << 8;
    char* Ec = E[ci & 1];
    // ---- S-GEMM: m = c (2 frags/wave), n = q, K = d = 128
    f32x4 accS[2] = {};
#pragma unroll
    for (int cfi = 0; cfi < 2; ++cfi) {
      const int c_l = w * 32 + cfi * 16 + ln;
      const u16* Ap = Ctb + ((size_t)(b_loc * 2048 + cg + c_l)) * 128;
#pragma unroll
      for (int kk = 0; kk < 4; ++kk) {
        const bf16x8 a = *(const bf16x8*)(Ap + kk * 32 + qt * 8);
        accS[cfi] = MFMA16(a, qwB[kk], accS[cfi]);
      }
    }
    // ---- exp; E = cmask?e (LDS, feeds T); eq kept in regs; l2 += cmask?e
#pragma unroll
    for (int cfi = 0; cfi < 2; ++cfi) {
      const int c_lE = w * 32 + cfi * 16 + qt * 4;
      const int cglob = b * 2048 + cg + c_lE;
      const f32x4 s0v = *(const f32x4*)(s0r + cglob);
      const f32x4 s0mv = *(const f32x4*)(s0m + cglob);
      float em[4], eq[4];
#pragma unroll
      for (int r = 0; r < 4; ++r) {
        const float e = __expf(accS[cfi][r] + s0v[r] + s1v);
        em[r] = (s0mv[r] > -1e29f) ? e : 0.f;
        l2a += em[r];
        eq[r] = qm ? e : 0.f;
      }
      const int chunkE = ((c_lE >> 3) ^ ln) & 31;
      uint2 pk = {pack_bf16(em[0], em[1]), pack_bf16(em[2], em[3])};
      *(uint2*)(Ec + ln * 512 + (chunkE << 4) + (c_lE & 7) * 2) = pk;
      eqp[ci][cfi].x = pack_bf16(eq[0], eq[1]);
      eqp[ci][cfi].y = pack_bf16(eq[2], eq[3]);
    }
    __syncthreads();
    // ---- T-GEMM: m = q (A = Ec), n = d (B = Cdb, global), K = c-tile 256
    {
      const int d = w * 16 + ln;
      const u16* Bp = Cdb + (size_t)b_loc * (128 * 2048) + (size_t)d * 2048 + cg;
#pragma unroll
      for (int kk = 0; kk < 8; ++kk) {
        const int c0ch = kk * 4 + qt;
        const bf16x8 aE = *(const bf16x8*)(Ec + ln * 512 + (((c0ch ^ ln) & 31) << 4));
        const bf16x8 bC = *(const bf16x8*)(Bp + kk * 32 + qt * 8);
        accT = MFMA16(aE, bC, accT);
      }
    }
    // no second barrier: next iter writes the OTHER E buffer; the single
    // barrier per iter orders write(i+2,same buf) after read(i) globally.
  }

  // ---- l2 reduce (qt groups via shfl, waves via LDS)
  {
    float v = l2a;
    v += __shfl_xor(v, 16);
    v += __shfl_xor(v, 32);
    if (l < 16) l2red[w * 16 + ln] = v;
  }
  __syncthreads();
  if (tid < 16) {
    float s = 0.f;
#pragma unroll
    for (int ww = 0; ww < 8; ++ww) s += l2red[ww * 16 + tid];
    l2L[tid] = 1.f / s;  // all-masked column impossible with given inputs
  }
  __syncthreads();
  // ---- Tdq[b_loc][d][q] = T/l2 (bf16)
  {
    const f32x4 inv = *(const f32x4*)(l2L + qt * 4);
    const float t0 = accT[0] * inv[0], t1 = accT[1] * inv[1];
    const float t2 = accT[2] * inv[2], t3 = accT[3] * inv[3];
    uint2 pk = {pack_bf16(t0, t1), pack_bf16(t2, t3)};
    *(uint2*)((char*)Tdq +
              (((size_t)(b_loc * 128 + w * 16 + ln)) * 256 + q0g + qt * 4) * 2) = pk;
  }
  // ---- deferred Praw burst (no barriers after; drains at kernel end)
#pragma unroll
  for (int ci = 0; ci < 8; ++ci)
#pragma unroll
    for (int cfi = 0; cfi < 2; ++cfi) {
      const int c0 = ci * 256 + w * 32 + cfi * 16 + qt * 4;
      u16* Pp = Praw + ((size_t)(b_loc * 2048 + c0)) * 256 + q0g + ln;
      const uint2 v = eqp[ci][cfi];
      Pp[0] = (u16)(v.x & 0xffffu);
      Pp[256] = (u16)(v.x >> 16);
      Pp[512] = (u16)(v.y & 0xffffu);
      Pp[768] = (u16)(v.y >> 16);
    }
}

// ------------------ k2: l1, A, Bt, epilogue (per pass) -----------------------
// grid nb*32; 512 thr. P tile staged in swizzled LDS; epilogue via LDS
// transpose (aliases P) with f32x4 reads/writes throughout.
__global__ void __launch_bounds__(512) k2(
    const float* __restrict__ C, const u16* __restrict__ Qdb,
    const u16* __restrict__ Tdq, const u16* __restrict__ Praw,
    float* __restrict__ out, int b0, int lg) {
  __shared__ __align__(16) u16 Plds[64 * 256];  // 32KB; aliased as Tr (f32) later
  __shared__ float l1red[64][9];
  __shared__ float l1L[64];
  float* Tr = (float*)Plds;

  const int tid = threadIdx.x, w = tid >> 6, l = tid & 63;
  const int qt = l >> 4, ln = l & 15;
  const int p = blockIdx.x;
  const int b_loc = p & ((1 << lg) - 1);
  const int ct = p >> lg;
  const int b = b0 + b_loc;
  const int cg = ct << 6;
  const int d0 = w * 16;

  // ---- stage P tile (64c x 256q bf16) -> swizzled LDS (coalesced uint4)
  {
    const u16* Pg = Praw + ((size_t)(b_loc * 2048 + cg)) * 256;
#pragma unroll
    for (int i = 0; i < 4; ++i) {
      const int o = tid * 8 + i * 4096;  // u16 units
      const int c = o >> 8, ch = (o & 255) >> 3;
      const uint4 v = *(const uint4*)(Pg + o);
      *(uint4*)&Plds[c * 256 + (((ch ^ (c & 31)) & 31) << 3)] = v;
    }
  }
  __syncthreads();

  // ---- l1 rowsums from LDS
  {
    const int r = tid >> 3, s8 = tid & 7;
    float s = 0.f;
#pragma unroll
    for (int jj = 0; jj < 4; ++jj) {
      const int ch = s8 * 4 + jj;
      const uint4 v = *(const uint4*)&Plds[r * 256 + (((ch ^ (r & 31)) & 31) << 3)];
      s += bf2f(v.x & 0xffffu) + bf2f(v.x >> 16);
      s += bf2f(v.y & 0xffffu) + bf2f(v.y >> 16);
      s += bf2f(v.z & 0xffffu) + bf2f(v.z >> 16);
      s += bf2f(v.w & 0xffffu) + bf2f(v.w >> 16);
    }
    l1red[r][s8] = s;
  }
  __syncthreads();
  if (tid < 64) {
    float x = 0.f;
#pragma unroll
    for (int j = 0; j < 8; ++j) x += l1red[tid][j];
    l1L[tid] = 1.f / x;  // visible to all after the pass-0 barrier below
  }

  // ---- streaming GEMMs: A-frags global (L2-hot), B-frags from LDS
  f32x4 accA[4] = {}, accB[4] = {};
  const u16* Qp = Qdb + ((size_t)(b * 128 + d0 + ln)) * 256;
  const u16* Tp = Tdq + ((size_t)(b_loc * 128 + d0 + ln)) * 256;
#pragma unroll
  for (int kt = 0; kt < 8; ++kt) {
    const int qo = kt * 32 + qt * 8;
    const bf16x8 aQ = *(const bf16x8*)(Qp + qo);
    const bf16x8 aT = *(const bf16x8*)(Tp + qo);
    const int ch = kt * 4 + qt;
#pragma unroll
    for (int cfi = 0; cfi < 4; ++cfi) {
      const int c = cfi * 16 + ln;
      const bf16x8 pB = *(const bf16x8*)&Plds[c * 256 + (((ch ^ (c & 31)) & 31) << 3)];
      accA[cfi] = MFMA16(aQ, pB, accA[cfi]);
      accB[cfi] = MFMA16(aT, pB, accB[cfi]);
    }
  }

  // ---- epilogue: two passes through the Tr transpose buffer (aliases Plds)
  const float* Cb = C + ((size_t)b * 128) * 2048 + cg;
  float* ob = out + ((size_t)b * 512) * 2048 + cg;
#pragma unroll
  for (int pass = 0; pass < 2; ++pass) {
    __syncthreads();  // Plds reads (pass 0) / prev Tr reads (pass 1) done
#pragma unroll
    for (int cfi = 0; cfi < 4; ++cfi) {
      const int c = cfi * 16 + ln;
      const float inv = l1L[c];
#pragma unroll
      for (int r = 0; r < 4; ++r) {
        const int d = d0 + qt * 4 + r;
        const float v = (pass ? accB[cfi][r] : accA[cfi][r]) * inv;
        Tr[d * 64 + (c ^ ((d & 7) << 2))] = v;
      }
    }
    __syncthreads();
    {
      const int d = tid >> 2, j = tid & 3;
#pragma unroll
      for (int k = 0; k < 4; ++k) {
        const int c4 = j * 16 + k * 4;
        const f32x4 val = *(const f32x4*)&Tr[d * 64 + (c4 ^ ((d & 7) << 2))];
        const f32x4 cv = *(const f32x4*)(Cb + (size_t)d * 2048 + c4);
        float* orow = ob + (size_t)d * 2048 + c4;
        if (pass == 0) {
          *(f32x4*)orow = cv;
          *(f32x4*)(orow + (size_t)128 * 2048) = val;
          const f32x4 ca = {cv[0] * val[0], cv[1] * val[1], cv[2] * val[2],
                            cv[3] * val[3]};
          *(f32x4*)(orow + (size_t)256 * 2048) = ca;
        } else {
          const f32x4 cbv = {cv[0] * val[0], cv[1] * val[1], cv[2] * val[2],
                             cv[3] * val[3]};
          *(f32x4*)(orow + (size_t)384 * 2048) = cbv;
        }
      }
    }
  }
}

// ======================= fp32 FALLBACK (round-1, verified) ==================
__device__ __forceinline__ int toff(int r, int d) {
  return r * 128 + ((((d >> 2) ^ ((r >> 2) & 7)) << 2) | (d & 3));
}
__device__ __forceinline__ int toff4(int r, int dc) {
  return r * 128 + ((dc ^ ((r >> 2) & 7)) << 2);
}

__global__ void __launch_bounds__(256) fb_sub0(const float* __restrict__ C,
                                               const float* __restrict__ w4C,
                                               const float* __restrict__ bias,
                                               float* __restrict__ sub0) {
  const int idx = blockIdx.x * 256 + threadIdx.x;
  const int b = idx >> 11, c = idx & 2047;
  const float* cp = C + (size_t)b * (128 * (size_t)2048) + c;
  float s = bias[0];
#pragma unroll 16
  for (int d = 0; d < 128; ++d) s += cp[(size_t)d * 2048] * w4C[d];
  sub0[idx] = s;
}

__global__ void __launch_bounds__(256) fb_sub1(const float* __restrict__ Q,
                                               const float* __restrict__ w4Q,
                                               float* __restrict__ sub1) {
  const int idx = blockIdx.x * 256 + threadIdx.x;
  const int b = idx >> 8, q = idx & 255;
  const float* qp = Q + (size_t)b * (128 * 256) + q;
  float s = 0.f;
#pragma unroll 16
  for (int d = 0; d < 128; ++d) s += qp[d * 256] * w4Q[d];
  sub1[idx] = s;
}

#define FB1_LDS_FLOATS (4096 + 16384 + 4224 + 32 + 32 + 128 + 128)

__global__ void __launch_bounds__(256, 1) fb_k1(
    const float* __restrict__ C, const float* __restrict__ Q,
    const int* __restrict__ Cmask, const float* __restrict__ w4mlu,
    const float* __restrict__ sub0, const float* __restrict__ sub1,
    float* __restrict__ Tws) {
  extern __shared__ float lds[];
  float* Qw = lds;
  float* Ct = lds + 4096;
  float* eL = Ct + 16384;
  float* l2L = eL + 4224;
  float* s1L = l2L + 32;
  float* s0L = s1L + 32;
  float* w4L = s0L + 128;

  const int tid = threadIdx.x;
  const int b = blockIdx.x >> 3;
  const int q0g = (blockIdx.x & 7) << 5;
  const float* Cb = C + (size_t)b * (128 * (size_t)2048);
  const float* Qb = Q + (size_t)b * (128 * 256);

  if (tid < 128) w4L[tid] = w4mlu[tid];
  if (tid >= 128 && tid < 160) s1L[tid - 128] = sub1[b * 256 + q0g + (tid - 128)];
  __syncthreads();
  {
    const int q = tid & 31;
    const int db = tid >> 5;
#pragma unroll
    for (int k = 0; k < 16; ++k) {
      const int d = db + (k << 3);
      Qw[toff(q, d)] = Qb[d * 256 + q0g + q] * w4L[d];
    }
  }
  const int i0 = tid & 31, j0 = tid >> 5;
  const int c0 = i0 << 2, q0 = j0 << 2;
  const int qi = tid & 15, dgrp = tid >> 4;
  const int q0t = qi << 1, d0 = dgrp << 3;

  float Tacc[2][8];
#pragma unroll
  for (int j = 0; j < 2; ++j)
#pragma unroll
    for (int e = 0; e < 8; ++e) Tacc[j][e] = 0.f;
  float l2a0 = 0.f, l2a1 = 0.f;

  for (int ci = 0; ci < 16; ++ci) {
    const int cgf = ci << 7;
    __syncthreads();
    {
      const int c = tid & 127;
      const int db = tid >> 7;
#pragma unroll 8
      for (int k = 0; k < 64; ++k) {
        const int d = db + (k << 1);
        Ct[toff(c, d)] = Cb[(size_t)d * 2048 + cgf + c];
      }
      if (tid < 128) {
        const int cc = cgf + tid;
        s0L[tid] = Cmask[b * 2048 + cc] ? sub0[b * 2048 + cc] : -1e30f;
      }
    }
    __syncthreads();
    float acc[4][4];
#pragma unroll
    for (int i = 0; i < 4; ++i)
#pragma unroll
      for (int j = 0; j < 4; ++j) acc[i][j] = 0.f;
#pragma unroll 4
    for (int dc = 0; dc < 32; ++dc) {
      float4 qv[4];
#pragma unroll
      for (int j = 0; j < 4; ++j) qv[j] = *(const float4*)&Qw[toff4(q0 + j, dc)];
#pragma unroll
      for (int i = 0; i < 4; ++i) {
        const float4 cvv = *(const float4*)&Ct[toff4(c0 + i, dc)];
#pragma unroll
        for (int j = 0; j < 4; ++j)
          acc[i][j] += cvv.x * qv[j].x + cvv.y * qv[j].y + cvv.z * qv[j].z + cvv.w * qv[j].w;
      }
    }
#pragma unroll
    for (int i = 0; i < 4; ++i) {
      const float s0v = s0L[c0 + i];
#pragma unroll
      for (int j = 0; j < 4; ++j)
        eL[(c0 + i) * 33 + q0 + j] = __expf(acc[i][j] + s0v + s1L[q0 + j]);
    }
    __syncthreads();
#pragma unroll 4
    for (int c = 0; c < 128; ++c) {
      const float ev0 = eL[c * 33 + q0t];
      const float ev1 = eL[c * 33 + q0t + 1];
      if (dgrp == 0) { l2a0 += ev0; l2a1 += ev1; }
      const int sw = (c >> 2) & 7;
      const float4 ca = *(const float4*)&Ct[c * 128 + ((((dgrp << 1)) ^ sw) << 2)];
      const float4 cb2 = *(const float4*)&Ct[c * 128 + ((((dgrp << 1) | 1) ^ sw) << 2)];
      Tacc[0][0] += ev0 * ca.x; Tacc[0][1] += ev0 * ca.y;
      Tacc[0][2] += ev0 * ca.z; Tacc[0][3] += ev0 * ca.w;
      Tacc[0][4] += ev0 * cb2.x; Tacc[0][5] += ev0 * cb2.y;
      Tacc[0][6] += ev0 * cb2.z; Tacc[0][7] += ev0 * cb2.w;
      Tacc[1][0] += ev1 * ca.x; Tacc[1][1] += ev1 * ca.y;
      Tacc[1][2] += ev1 * ca.z; Tacc[1][3] += ev1 * ca.w;
      Tacc[1][4] += ev1 * cb2.x; Tacc[1][5] += ev1 * cb2.y;
      Tacc[1][6] += ev1 * cb2.z; Tacc[1][7] += ev1 * cb2.w;
    }
  }
  if (dgrp == 0) { l2L[q0t] = l2a0; l2L[q0t + 1] = l2a1; }
  __syncthreads();
  {
    const float inv0 = 1.f / l2L[q0t];
    const float inv1 = 1.f / l2L[q0t + 1];
    const size_t tb = ((size_t)b * 256 + q0g + q0t) * 128 + d0;
    float4 wv;
    wv.x = Tacc[0][0] * inv0; wv.y = Tacc[0][1] * inv0; wv.z = Tacc[0][2] * inv0; wv.w = Tacc[0][3] * inv0;
    *(float4*)&Tws[tb] = wv;
    wv.x = Tacc[0][4] * inv0; wv.y = Tacc[0][5] * inv0; wv.z = Tacc[0][6] * inv0; wv.w = Tacc[0][7] * inv0;
    *(float4*)&Tws[tb + 4] = wv;
    wv.x = Tacc[1][0] * inv1; wv.y = Tacc[1][1] * inv1; wv.z = Tacc[1][2] * inv1; wv.w = Tacc[1][3] * inv1;
    *(float4*)&Tws[tb + 128] = wv;
    wv.x = Tacc[1][4] * inv1; wv.y = Tacc[1][5] * inv1; wv.z = Tacc[1][6] * inv1; wv.w = Tacc[1][7] * inv1;
    *(float4*)&Tws[tb + 132] = wv;
  }
}

#define FB2_LDS_FLOATS (8192 + 8192 + 17408 + 256 + 64 + 64 + 256 + 128)

__global__ void __launch_bounds__(256, 1) fb_k2(
    const float* __restrict__ C, const float* __restrict__ Q,
    const int* __restrict__ Qmask, const float* __restrict__ w4mlu,
    const float* __restrict__ sub0, const float* __restrict__ sub1,
    const float* __restrict__ Tws, float* __restrict__ out) {
  extern __shared__ float lds[];
  float* Ct = lds;
  float* St = Ct + 8192;
  float* P = St + 8192;
  float* redL = P + 17408;
  float* l1L = redL + 256;
  float* s0L = l1L + 64;
  float* s1L = s0L + 64;
  float* w4L = s1L + 256;

  const int tid = threadIdx.x;
  const int b = blockIdx.x >> 5;
  const int c0g = (blockIdx.x & 31) << 6;
  const float* Cb = C + (size_t)b * (128 * (size_t)2048);
  const float* Qb = Q + (size_t)b * (128 * 256);

  s1L[tid] = sub1[b * 256 + tid] + (Qmask[b * 256 + tid] ? 0.f : -1e30f);
  if (tid < 64) s0L[tid] = sub0[b * 2048 + c0g + tid];
  if (tid >= 128 && tid < 256) w4L[tid - 128] = w4mlu[tid - 128];
  {
    const int c = tid & 63;
    const int db = tid >> 6;
#pragma unroll 8
    for (int k = 0; k < 32; ++k) {
      const int d = db + (k << 2);
      Ct[toff(c, d)] = Cb[(size_t)d * 2048 + c0g + c];
    }
  }
  __syncthreads();

  const int i0 = tid & 15, j0 = tid >> 4;
  const int c0 = i0 << 2, q0 = j0 << 2;
  const int dg = j0, d0 = j0 << 3;

  for (int qtc = 0; qtc < 4; ++qtc) {
    {
      const int q = tid & 63;
      const int db = tid >> 6;
#pragma unroll 8
      for (int k = 0; k < 32; ++k) {
        const int d = db + (k << 2);
        St[toff(q, d)] = Qb[d * 256 + (qtc << 6) + q] * w4L[d];
      }
    }
    __syncthreads();
    float acc[4][4];
#pragma unroll
    for (int i = 0; i < 4; ++i)
#pragma unroll
      for (int j = 0; j < 4; ++j) acc[i][j] = 0.f;
#pragma unroll 4
    for (int dc = 0; dc < 32; ++dc) {
      float4 qv[4];
#pragma unroll
      for (int j = 0; j < 4; ++j) qv[j] = *(const float4*)&St[toff4(q0 + j, dc)];
#pragma unroll
      for (int i = 0; i < 4; ++i) {
        const float4 cvv = *(const float4*)&Ct[toff4(c0 + i, dc)];
#pragma unroll
        for (int j = 0; j < 4; ++j)
          acc[i][j] += cvv.x * qv[j].x + cvv.y * qv[j].y + cvv.z * qv[j].z + cvv.w * qv[j].w;
      }
    }
#pragma unroll
    for (int j = 0; j < 4; ++j) {
      const int qq = (qtc << 6) + q0 + j;
      const float s1v = s1L[qq];
      float4 pv;
      pv.x = __expf(acc[0][j] + s0L[c0 + 0] + s1v);
      pv.y = __expf(acc[1][j] + s0L[c0 + 1] + s1v);
      pv.z = __expf(acc[2][j] + s0L[c0 + 2] + s1v);
      pv.w = __expf(acc[3][j] + s0L[c0 + 3] + s1v);
      *(float4*)&P[qq * 68 + c0] = pv;
    }
    __syncthreads();
  }
  {
    const int c = tid & 63, g = tid >> 6;
    float s = 0.f;
#pragma unroll 8
    for (int q = 0; q < 64; ++q) s += P[((g << 6) + q) * 68 + c];
    redL[tid] = s;
  }
  __syncthreads();
  if (tid < 64) l1L[tid] = 1.f / (redL[tid] + redL[64 + tid] + redL[128 + tid] + redL[192 + tid]);

  float accA[4][8];
#pragma unroll
  for (int i = 0; i < 4; ++i)
#pragma unroll
    for (int e = 0; e < 8; ++e) accA[i][e] = 0.f;
  for (int qtc = 0; qtc < 4; ++qtc) {
    __syncthreads();
    {
      const int q = tid & 63;
      const int db = tid >> 6;
#pragma unroll 8
      for (int k = 0; k < 32; ++k) {
        const int d = db + (k << 2);
        St[toff(q, d)] = Qb[d * 256 + (qtc << 6) + q];
      }
    }
    __syncthreads();
#pragma unroll 2
    for (int q = 0; q < 64; ++q) {
      const int qq = (qtc << 6) + q;
      const float4 pv = *(const float4*)&P[qq * 68 + c0];
      const int sw = (q >> 2) & 7;
      const float4 qa = *(const float4*)&St[q * 128 + ((((dg << 1)) ^ sw) << 2)];
      const float4 qb2 = *(const float4*)&St[q * 128 + ((((dg << 1) | 1) ^ sw) << 2)];
      const float pf[4] = {pv.x, pv.y, pv.z, pv.w};
      const float qf[8] = {qa.x, qa.y, qa.z, qa.w, qb2.x, qb2.y, qb2.z, qb2.w};
#pragma unroll
      for (int i = 0; i < 4; ++i)
#pragma unroll
        for (int e = 0; e < 8; ++e) accA[i][e] += pf[i] * qf[e];
    }
  }
  float accB[4][8];
#pragma unroll
  for (int i = 0; i < 4; ++i)
#pragma unroll
    for (int e = 0; e < 8; ++e) accB[i][e] = 0.f;
  for (int qtc = 0; qtc < 4; ++qtc) {
    __syncthreads();
    {
      const int dc = tid & 31;
      const int q0r = tid >> 5;
#pragma unroll
      for (int k = 0; k < 8; ++k) {
        const int q = q0r + (k << 3);
        const float4 tv = *(const float4*)&Tws[((size_t)b * 256 + (qtc << 6) + q) * 128 + (dc << 2)];
        *(float4*)&St[q * 128 + ((dc ^ ((q >> 2) & 7)) << 2)] = tv;
      }
    }
    __syncthreads();
#pragma unroll 2
    for (int q = 0; q < 64; ++q) {
      const int qq = (qtc << 6) + q;
      const float4 pv = *(const float4*)&P[qq * 68 + c0];
      const int sw = (q >> 2) & 7;
      const float4 qa = *(const float4*)&St[q * 128 + ((((dg << 1)) ^ sw) << 2)];
      const float4 qb2 = *(const float4*)&St[q * 128 + ((((dg << 1) | 1) ^ sw) << 2)];
      const float pf[4] = {pv.x, pv.y, pv.z, pv.w};
      const float qf[8] = {qa.x, qa.y, qa.z, qa.w, qb2.x, qb2.y, qb2.z, qb2.w};
#pragma unroll
      for (int i = 0; i < 4; ++i)
#pragma unroll
        for (int e = 0; e < 8; ++e) accB[i][e] += pf[i] * qf[e];
    }
  }
  __syncthreads();
  {
    float* Al = St;
    float* Bl = P;
#pragma unroll
    for (int i = 0; i < 4; ++i) {
      const float inv = l1L[c0 + i];
#pragma unroll
      for (int e = 0; e < 8; ++e) {
        Al[(d0 + e) * 64 + c0 + i] = accA[i][e] * inv;
        Bl[(d0 + e) * 64 + c0 + i] = accB[i][e] * inv;
      }
    }
  }
  __syncthreads();
  {
    const float* Al = St;
    const float* Bl = P;
    const int c = tid & 63;
    const int db = tid >> 6;
    const size_t ob = (size_t)b * (512 * 2048) + c0g + c;
#pragma unroll 4
    for (int k = 0; k < 32; ++k) {
      const int d = db + (k << 2);
      const float cvv = Ct[toff(c, d)];
      const float av = Al[d * 64 + c];
      const float bv = Bl[d * 64 + c];
      out[ob + (size_t)d * 2048] = cvv;
      out[ob + (size_t)(128 + d) * 2048] = av;
      out[ob + (size_t)(256 + d) * 2048] = cvv * av;
      out[ob + (size_t)(384 + d) * 2048] = cvv * bv;
    }
  }
}

// ------------------------------ launcher ------------------------------------
extern "C" void kernel_launch(void* const* d_in, const int* in_sizes, int n_in,
                              void* d_out, int out_size, void* d_ws, size_t ws_size,
                              hipStream_t stream) {
  (void)in_sizes; (void)n_in; (void)out_size;
  const float* C = (const float*)d_in[0];
  const float* Q = (const float*)d_in[1];
  const int* Cmask = (const int*)d_in[2];
  const int* Qmask = (const int*)d_in[3];
  const float* w4C = (const float*)d_in[4];
  const float* w4Q = (const float*)d_in[5];
  const float* w4mlu = (const float*)d_in[6];
  const float* bias = (const float*)d_in[7];
  float* out = (float*)d_out;
  char* wsb = (char*)d_ws;

  const size_t NEED_FULL = 73990144;
  const size_t NEED_HALF = 39518208;

  if (ws_size >= NEED_FULL) {
    u16* Ctb = (u16*)(wsb + 0);
    u16* Cdb = (u16*)(wsb + 16777216);
    u16* Qwb = (u16*)(wsb + 33554432);
    u16* Qdb = (u16*)(wsb + 35651584);
    u16* Tdq = (u16*)(wsb + 37748736);
    u16* Praw = (u16*)(wsb + 39845888);
    float* s0r = (float*)(wsb + 73400320);
    float* s0m = (float*)(wsb + 73662464);
    float* s1r = (float*)(wsb + 73924608);
    float* s1m = (float*)(wsb + 73957376);

    prepQ<<<32, 512, 0, stream>>>(Q, Qmask, w4Q, w4mlu, Qwb, Qdb, s1r, s1m);
    prepC<<<256, 512, 0, stream>>>(C, Cmask, w4C, bias, Ctb, Cdb, s0r, s0m, 0, 5);
    k1<<<512, 512, 0, stream>>>(Ctb, Cdb, Qwb, s0r, s0m, s1r, s1m, Tdq, Praw, 0, 5);
    k2<<<1024, 512, 0, stream>>>(C, Qdb, Tdq, Praw, out, 0, 5);
  } else if (ws_size >= NEED_HALF) {
    u16* Ctb = (u16*)(wsb + 0);
    u16* Cdb = (u16*)(wsb + 8388608);
    u16* Qwb = (u16*)(wsb + 16777216);
    u16* Qdb = (u16*)(wsb + 18874368);
    u16* Tdq = (u16*)(wsb + 20971520);
    u16* Praw = (u16*)(wsb + 22020096);
    float* s0r = (float*)(wsb + 38928384);
    float* s0m = (float*)(wsb + 39190528);
    float* s1r = (float*)(wsb + 39452672);
    float* s1m = (float*)(wsb + 39485440);

    prepQ<<<32, 512, 0, stream>>>(Q, Qmask, w4Q, w4mlu, Qwb, Qdb, s1r, s1m);
    for (int h = 0; h < 2; ++h) {
      prepC<<<128, 512, 0, stream>>>(C, Cmask, w4C, bias, Ctb, Cdb, s0r, s0m,
                                     16 * h, 4);
      k1<<<256, 512, 0, stream>>>(Ctb, Cdb, Qwb, s0r, s0m, s1r, s1m, Tdq, Praw,
                                  16 * h, 4);
      k2<<<512, 512, 0, stream>>>(C, Qdb, Tdq, Praw, out, 16 * h, 4);
    }
  } else {
    float* ws = (float*)d_ws;
    float* sub0 = ws;
    float* sub1 = ws + 65536;
    float* Tws = ws + 73728;
    (void)hipFuncSetAttribute(reinterpret_cast<const void*>(fb_k1),
                              hipFuncAttributeMaxDynamicSharedMemorySize,
                              (int)(FB1_LDS_FLOATS * sizeof(float)));
    (void)hipFuncSetAttribute(reinterpret_cast<const void*>(fb_k2),
                              hipFuncAttributeMaxDynamicSharedMemorySize,
                              (int)(FB2_LDS_FLOATS * sizeof(float)));
    fb_sub0<<<256, 256, 0, stream>>>(C, w4C, bias, sub0);
    fb_sub1<<<32, 256, 0, stream>>>(Q, w4Q, sub1);
    fb_k1<<<256, 256, FB1_LDS_FLOATS * sizeof(float), stream>>>(C, Q, Cmask, w4mlu,
                                                                sub0, sub1, Tws);
    fb_k2<<<1024, 256, FB2_LDS_FLOATS * sizeof(float), stream>>>(C, Q, Qmask, w4mlu,
                                                                 sub0, sub1, Tws, out);
  }
}

// Round 9
// 166.283 us; speedup vs baseline: 1.0423x; 1.0423x over previous
//
#include <hip/hip_runtime.h>
#include <hip/hip_bf16.h>

// CQAttention B=32 D=128 Lc=2048 Lq=256 — bf16 MFMA, P-materialized pipeline v5.
//
// vs v4 (round 8): k1 restructured to TWO PHASES with E = full [16 q][2048 c]
// bf16 (64KB LDS): phase A = all 8 S-GEMM tiles (no barriers, 128 independent
// global loads + 64 MFMAs pipelined), ONE barrier, phase B = all 64 T-GEMM
// MFMAs (E from LDS + Cdb from L2). Barriers per block: 10 -> 3. Praw cached
// in regs during phase A, burst-stored at the end (round-8-proven). k2, preps,
// tiers unchanged from round 8 (passed, absmax 0.0625).

typedef unsigned short u16;
typedef short bf16x8 __attribute__((ext_vector_type(8)));
typedef float f32x4 __attribute__((ext_vector_type(4)));

#define MFMA16(a, b, c) __builtin_amdgcn_mfma_f32_16x16x32_bf16(a, b, c, 0, 0, 0)

__device__ __forceinline__ unsigned pack_bf16(float a, float b) {
  __hip_bfloat16 ha = __float2bfloat16(a), hb = __float2bfloat16(b);
  unsigned short ua = __builtin_bit_cast(unsigned short, ha);
  unsigned short ub = __builtin_bit_cast(unsigned short, hb);
  return (unsigned)ua | ((unsigned)ub << 16);
}
__device__ __forceinline__ u16 bf16u(float a) {
  __hip_bfloat16 h = __float2bfloat16(a);
  return __builtin_bit_cast(unsigned short, h);
}
__device__ __forceinline__ float bf2f(unsigned x) {
  unsigned v = x << 16;
  return __builtin_bit_cast(float, v);
}

// ------------------------ prepC: per pass, 512 thr --------------------------
__global__ void __launch_bounds__(512) prepC(const float* __restrict__ C,
                                             const int* __restrict__ Cmask,
                                             const float* __restrict__ w4C,
                                             const float* __restrict__ bias,
                                             u16* __restrict__ Ctb,
                                             u16* __restrict__ Cdb,
                                             float* __restrict__ s0r,
                                             float* __restrict__ s0m,
                                             int b0, int lg) {
  __shared__ float wL[128];
  __shared__ float red[512];
  const int t = threadIdx.x;
  const int c_loc = t & 255, dh = t >> 8;
  const int b_loc = blockIdx.x & ((1 << lg) - 1), ct = blockIdx.x >> lg;
  const int b = b0 + b_loc;
  const int c = ct * 256 + c_loc;
  if (t < 128) wL[t] = w4C[t];
  __syncthreads();
  const float* src = C + (size_t)b * (128 * 2048) + c;
  u16* dstT = Ctb + ((size_t)(b_loc * 2048 + c)) * 128;
  u16* dstD = Cdb + (size_t)b_loc * (128 * 2048) + c;
  float s = 0.f;
#pragma unroll
  for (int dg = 0; dg < 8; ++dg) {
    const int d0 = dh * 64 + dg * 8;
    float v[8];
#pragma unroll
    for (int i = 0; i < 8; ++i) v[i] = src[(size_t)(d0 + i) * 2048];
#pragma unroll
    for (int i = 0; i < 8; ++i) s += v[i] * wL[d0 + i];
    uint4 o = {pack_bf16(v[0], v[1]), pack_bf16(v[2], v[3]),
               pack_bf16(v[4], v[5]), pack_bf16(v[6], v[7])};
    *(uint4*)(dstT + d0) = o;
    const u16* ou = (const u16*)&o;
#pragma unroll
    for (int i = 0; i < 8; ++i) dstD[(size_t)(d0 + i) * 2048] = ou[i];
  }
  red[t] = s;
  __syncthreads();
  if (t < 256) {
    const int idx = b * 2048 + ct * 256 + t;
    const float tot = red[t] + red[t + 256] + bias[0];
    s0r[idx] = tot;
    s0m[idx] = Cmask[idx] ? tot : -1e30f;
  }
}

// --------------------------- prepQ: all b, once -----------------------------
__global__ void __launch_bounds__(512) prepQ(const float* __restrict__ Q,
                                             const int* __restrict__ Qmask,
                                             const float* __restrict__ w4Q,
                                             const float* __restrict__ w4mlu,
                                             u16* __restrict__ Qwb,
                                             u16* __restrict__ Qdb,
                                             float* __restrict__ s1r,
                                             float* __restrict__ s1m) {
  __shared__ float wqL[128], wmL[128];
  __shared__ float red[512];
  const int t = threadIdx.x;
  const int q = t & 255, dh = t >> 8;
  const int b = blockIdx.x;
  if (t < 128) { wqL[t] = w4Q[t]; wmL[t] = w4mlu[t]; }
  __syncthreads();
  const float* src = Q + (size_t)b * (128 * 256) + q;
  u16* dstW = Qwb + ((size_t)(b * 256 + q)) * 128;
  u16* dstD = Qdb + (size_t)b * (128 * 256) + q;
  float s = 0.f;
#pragma unroll
  for (int dg = 0; dg < 8; ++dg) {
    const int d0 = dh * 64 + dg * 8;
    float v[8];
#pragma unroll
    for (int i = 0; i < 8; ++i) v[i] = src[(d0 + i) * 256];
#pragma unroll
    for (int i = 0; i < 8; ++i) s += v[i] * wqL[d0 + i];
#pragma unroll
    for (int i = 0; i < 8; ++i) dstD[(d0 + i) * 256] = bf16u(v[i]);
    float wv[8];
#pragma unroll
    for (int i = 0; i < 8; ++i) wv[i] = v[i] * wmL[d0 + i];
    uint4 o = {pack_bf16(wv[0], wv[1]), pack_bf16(wv[2], wv[3]),
               pack_bf16(wv[4], wv[5]), pack_bf16(wv[6], wv[7])};
    *(uint4*)(dstW + d0) = o;
  }
  red[t] = s;
  __syncthreads();
  if (t < 256) {
    const int idx = b * 256 + t;
    const float tot = red[t] + red[t + 256];
    s1r[idx] = tot;
    s1m[idx] = Qmask[idx] ? tot : -1e30f;
  }
}

// ------------------- k1: two-phase S/exp then T (per pass) -------------------
// grid nb*16; 512 thr (8 waves). E = [16 q][2048 c] bf16, chunk-swizzled, 64KB.
__global__ void __launch_bounds__(512) k1(
    const u16* __restrict__ Ctb, const u16* __restrict__ Cdb,
    const u16* __restrict__ Qwb, const float* __restrict__ s0r,
    const float* __restrict__ s0m, const float* __restrict__ s1r,
    const float* __restrict__ s1m, u16* __restrict__ Tdq,
    u16* __restrict__ Praw, int b0, int lg) {
  __shared__ __align__(16) char E[16 * 4096];  // 64KB
  __shared__ float l2red[128];
  __shared__ float l2L[16];

  const int tid = threadIdx.x, w = tid >> 6, l = tid & 63;
  const int qt = l >> 4, ln = l & 15;
  const int p = blockIdx.x;
  const int b_loc = p & ((1 << lg) - 1);  // same b_loc -> same XCD
  const int q0g = (p >> lg) << 4;
  const int b = b0 + b_loc;

  // Qw B-frags: B[k=d][n=q], lane ln = q
  bf16x8 qwB[4];
  {
    const u16* Qwp = Qwb + ((size_t)(b * 256 + q0g + ln)) * 128;
#pragma unroll
    for (int kk = 0; kk < 4; ++kk) qwB[kk] = *(const bf16x8*)(Qwp + kk * 32 + qt * 8);
  }
  const float s1v = s1r[b * 256 + q0g + ln];
  const bool qm = s1m[b * 256 + q0g + ln] > -1e29f;

  f32x4 accT = {};   // T[q = qt*4+r][d = w*16+ln]
  float l2a = 0.f;
  uint2 eqp[8][2];   // deferred Praw values (qmask'd), packed bf16

  // ---- phase A: all 8 S-GEMM tiles, exp, E writes — NO barriers
#pragma unroll
  for (int ci = 0; ci < 8; ++ci) {
    const int cg = ci << 8;
    f32x4 accS[2] = {};
#pragma unroll
    for (int cfi = 0; cfi < 2; ++cfi) {
      const int c_l = w * 32 + cfi * 16 + ln;
      const u16* Ap = Ctb + ((size_t)(b_loc * 2048 + cg + c_l)) * 128;
#pragma unroll
      for (int kk = 0; kk < 4; ++kk) {
        const bf16x8 a = *(const bf16x8*)(Ap + kk * 32 + qt * 8);
        accS[cfi] = MFMA16(a, qwB[kk], accS[cfi]);
      }
    }
#pragma unroll
    for (int cfi = 0; cfi < 2; ++cfi) {
      const int c_lE = w * 32 + cfi * 16 + qt * 4;
      const int cglob = b * 2048 + cg + c_lE;
      const f32x4 s0v = *(const f32x4*)(s0r + cglob);
      const f32x4 s0mv = *(const f32x4*)(s0m + cglob);
      float em[4], eq[4];
#pragma unroll
      for (int r = 0; r < 4; ++r) {
        const float e = __expf(accS[cfi][r] + s0v[r] + s1v);
        em[r] = (s0mv[r] > -1e29f) ? e : 0.f;
        l2a += em[r];
        eq[r] = qm ? e : 0.f;
      }
      // E[q=ln][c], chunk (c>>3) swizzled by ^ln within the 256-chunk row
      const int chg = (cg + c_lE) >> 3;
      uint2 pk = {pack_bf16(em[0], em[1]), pack_bf16(em[2], em[3])};
      *(uint2*)(E + ln * 4096 + (((chg ^ ln) & 255) << 4) + (c_lE & 7) * 2) = pk;
      eqp[ci][cfi].x = pack_bf16(eq[0], eq[1]);
      eqp[ci][cfi].y = pack_bf16(eq[2], eq[3]);
    }
  }
  __syncthreads();  // the ONLY main-loop barrier

  // ---- phase B: T-GEMM over all 2048 c (A = E from LDS, B = Cdb from L2)
  {
    const int d = w * 16 + ln;
    const u16* Bp = Cdb + (size_t)b_loc * (128 * 2048) + (size_t)d * 2048;
#pragma unroll
    for (int ci = 0; ci < 8; ++ci) {
#pragma unroll
      for (int kk = 0; kk < 8; ++kk) {
        const int chg = ci * 32 + kk * 4 + qt;
        const bf16x8 aE = *(const bf16x8*)(E + ln * 4096 + (((chg ^ ln) & 255) << 4));
        const bf16x8 bC = *(const bf16x8*)(Bp + ci * 256 + kk * 32 + qt * 8);
        accT = MFMA16(aE, bC, accT);
      }
    }
  }

  // ---- l2 reduce (qt groups via shfl, waves via LDS)
  {
    float v = l2a;
    v += __shfl_xor(v, 16);
    v += __shfl_xor(v, 32);
    if (l < 16) l2red[w * 16 + ln] = v;
  }
  __syncthreads();
  if (tid < 16) {
    float s = 0.f;
#pragma unroll
    for (int ww = 0; ww < 8; ++ww) s += l2red[ww * 16 + tid];
    l2L[tid] = 1.f / s;  // all-masked column impossible with given inputs
  }
  __syncthreads();
  // ---- Tdq[b_loc][d][q] = T/l2 (bf16)
  {
    const f32x4 inv = *(const f32x4*)(l2L + qt * 4);
    const float t0 = accT[0] * inv[0], t1 = accT[1] * inv[1];
    const float t2 = accT[2] * inv[2], t3 = accT[3] * inv[3];
    uint2 pk = {pack_bf16(t0, t1), pack_bf16(t2, t3)};
    *(uint2*)((char*)Tdq +
              (((size_t)(b_loc * 128 + w * 16 + ln)) * 256 + q0g + qt * 4) * 2) = pk;
  }
  // ---- deferred Praw burst (drains at kernel end)
#pragma unroll
  for (int ci = 0; ci < 8; ++ci)
#pragma unroll
    for (int cfi = 0; cfi < 2; ++cfi) {
      const int c0 = ci * 256 + w * 32 + cfi * 16 + qt * 4;
      u16* Pp = Praw + ((size_t)(b_loc * 2048 + c0)) * 256 + q0g + ln;
      const uint2 v = eqp[ci][cfi];
      Pp[0] = (u16)(v.x & 0xffffu);
      Pp[256] = (u16)(v.x >> 16);
      Pp[512] = (u16)(v.y & 0xffffu);
      Pp[768] = (u16)(v.y >> 16);
    }
}

// ------------------ k2: l1, A, Bt, epilogue (per pass) -----------------------
// grid nb*32; 512 thr. (unchanged from round 8 — passed)
__global__ void __launch_bounds__(512) k2(
    const float* __restrict__ C, const u16* __restrict__ Qdb,
    const u16* __restrict__ Tdq, const u16* __restrict__ Praw,
    float* __restrict__ out, int b0, int lg) {
  __shared__ __align__(16) u16 Plds[64 * 256];
  __shared__ float l1red[64][9];
  __shared__ float l1L[64];
  float* Tr = (float*)Plds;

  const int tid = threadIdx.x, w = tid >> 6, l = tid & 63;
  const int qt = l >> 4, ln = l & 15;
  const int p = blockIdx.x;
  const int b_loc = p & ((1 << lg) - 1);
  const int ct = p >> lg;
  const int b = b0 + b_loc;
  const int cg = ct << 6;
  const int d0 = w * 16;

  {
    const u16* Pg = Praw + ((size_t)(b_loc * 2048 + cg)) * 256;
#pragma unroll
    for (int i = 0; i < 4; ++i) {
      const int o = tid * 8 + i * 4096;
      const int c = o >> 8, ch = (o & 255) >> 3;
      const uint4 v = *(const uint4*)(Pg + o);
      *(uint4*)&Plds[c * 256 + (((ch ^ (c & 31)) & 31) << 3)] = v;
    }
  }
  __syncthreads();

  {
    const int r = tid >> 3, s8 = tid & 7;
    float s = 0.f;
#pragma unroll
    for (int jj = 0; jj < 4; ++jj) {
      const int ch = s8 * 4 + jj;
      const uint4 v = *(const uint4*)&Plds[r * 256 + (((ch ^ (r & 31)) & 31) << 3)];
      s += bf2f(v.x & 0xffffu) + bf2f(v.x >> 16);
      s += bf2f(v.y & 0xffffu) + bf2f(v.y >> 16);
      s += bf2f(v.z & 0xffffu) + bf2f(v.z >> 16);
      s += bf2f(v.w & 0xffffu) + bf2f(v.w >> 16);
    }
    l1red[r][s8] = s;
  }
  __syncthreads();
  if (tid < 64) {
    float x = 0.f;
#pragma unroll
    for (int j = 0; j < 8; ++j) x += l1red[tid][j];
    l1L[tid] = 1.f / x;
  }

  f32x4 accA[4] = {}, accB[4] = {};
  const u16* Qp = Qdb + ((size_t)(b * 128 + d0 + ln)) * 256;
  const u16* Tp = Tdq + ((size_t)(b_loc * 128 + d0 + ln)) * 256;
#pragma unroll
  for (int kt = 0; kt < 8; ++kt) {
    const int qo = kt * 32 + qt * 8;
    const bf16x8 aQ = *(const bf16x8*)(Qp + qo);
    const bf16x8 aT = *(const bf16x8*)(Tp + qo);
    const int ch = kt * 4 + qt;
#pragma unroll
    for (int cfi = 0; cfi < 4; ++cfi) {
      const int c = cfi * 16 + ln;
      const bf16x8 pB = *(const bf16x8*)&Plds[c * 256 + (((ch ^ (c & 31)) & 31) << 3)];
      accA[cfi] = MFMA16(aQ, pB, accA[cfi]);
      accB[cfi] = MFMA16(aT, pB, accB[cfi]);
    }
  }

  const float* Cb = C + ((size_t)b * 128) * 2048 + cg;
  float* ob = out + ((size_t)b * 512) * 2048 + cg;
#pragma unroll
  for (int pass = 0; pass < 2; ++pass) {
    __syncthreads();
#pragma unroll
    for (int cfi = 0; cfi < 4; ++cfi) {
      const int c = cfi * 16 + ln;
      const float inv = l1L[c];
#pragma unroll
      for (int r = 0; r < 4; ++r) {
        const int d = d0 + qt * 4 + r;
        const float v = (pass ? accB[cfi][r] : accA[cfi][r]) * inv;
        Tr[d * 64 + (c ^ ((d & 7) << 2))] = v;
      }
    }
    __syncthreads();
    {
      const int d = tid >> 2, j = tid & 3;
#pragma unroll
      for (int k = 0; k < 4; ++k) {
        const int c4 = j * 16 + k * 4;
        const f32x4 val = *(const f32x4*)&Tr[d * 64 + (c4 ^ ((d & 7) << 2))];
        const f32x4 cv = *(const f32x4*)(Cb + (size_t)d * 2048 + c4);
        float* orow = ob + (size_t)d * 2048 + c4;
        if (pass == 0) {
          *(f32x4*)orow = cv;
          *(f32x4*)(orow + (size_t)128 * 2048) = val;
          const f32x4 ca = {cv[0] * val[0], cv[1] * val[1], cv[2] * val[2],
                            cv[3] * val[3]};
          *(f32x4*)(orow + (size_t)256 * 2048) = ca;
        } else {
          const f32x4 cbv = {cv[0] * val[0], cv[1] * val[1], cv[2] * val[2],
                             cv[3] * val[3]};
          *(f32x4*)(orow + (size_t)384 * 2048) = cbv;
        }
      }
    }
  }
}

// ======================= fp32 FALLBACK (round-1, verified) ==================
__device__ __forceinline__ int toff(int r, int d) {
  return r * 128 + ((((d >> 2) ^ ((r >> 2) & 7)) << 2) | (d & 3));
}
__device__ __forceinline__ int toff4(int r, int dc) {
  return r * 128 + ((dc ^ ((r >> 2) & 7)) << 2);
}

__global__ void __launch_bounds__(256) fb_sub0(const float* __restrict__ C,
                                               const float* __restrict__ w4C,
                                               const float* __restrict__ bias,
                                               float* __restrict__ sub0) {
  const int idx = blockIdx.x * 256 + threadIdx.x;
  const int b = idx >> 11, c = idx & 2047;
  const float* cp = C + (size_t)b * (128 * (size_t)2048) + c;
  float s = bias[0];
#pragma unroll 16
  for (int d = 0; d < 128; ++d) s += cp[(size_t)d * 2048] * w4C[d];
  sub0[idx] = s;
}

__global__ void __launch_bounds__(256) fb_sub1(const float* __restrict__ Q,
                                               const float* __restrict__ w4Q,
                                               float* __restrict__ sub1) {
  const int idx = blockIdx.x * 256 + threadIdx.x;
  const int b = idx >> 8, q = idx & 255;
  const float* qp = Q + (size_t)b * (128 * 256) + q;
  float s = 0.f;
#pragma unroll 16
  for (int d = 0; d < 128; ++d) s += qp[d * 256] * w4Q[d];
  sub1[idx] = s;
}

#define FB1_LDS_FLOATS (4096 + 16384 + 4224 + 32 + 32 + 128 + 128)

__global__ void __launch_bounds__(256, 1) fb_k1(
    const float* __restrict__ C, const float* __restrict__ Q,
    const int* __restrict__ Cmask, const float* __restrict__ w4mlu,
    const float* __restrict__ sub0, const float* __restrict__ sub1,
    float* __restrict__ Tws) {
  extern __shared__ float lds[];
  float* Qw = lds;
  float* Ct = lds + 4096;
  float* eL = Ct + 16384;
  float* l2L = eL + 4224;
  float* s1L = l2L + 32;
  float* s0L = s1L + 32;
  float* w4L = s0L + 128;

  const int tid = threadIdx.x;
  const int b = blockIdx.x >> 3;
  const int q0g = (blockIdx.x & 7) << 5;
  const float* Cb = C + (size_t)b * (128 * (size_t)2048);
  const float* Qb = Q + (size_t)b * (128 * 256);

  if (tid < 128) w4L[tid] = w4mlu[tid];
  if (tid >= 128 && tid < 160) s1L[tid - 128] = sub1[b * 256 + q0g + (tid - 128)];
  __syncthreads();
  {
    const int q = tid & 31;
    const int db = tid >> 5;
#pragma unroll
    for (int k = 0; k < 16; ++k) {
      const int d = db + (k << 3);
      Qw[toff(q, d)] = Qb[d * 256 + q0g + q] * w4L[d];
    }
  }
  const int i0 = tid & 31, j0 = tid >> 5;
  const int c0 = i0 << 2, q0 = j0 << 2;
  const int qi = tid & 15, dgrp = tid >> 4;
  const int q0t = qi << 1, d0 = dgrp << 3;

  float Tacc[2][8];
#pragma unroll
  for (int j = 0; j < 2; ++j)
#pragma unroll
    for (int e = 0; e < 8; ++e) Tacc[j][e] = 0.f;
  float l2a0 = 0.f, l2a1 = 0.f;

  for (int ci = 0; ci < 16; ++ci) {
    const int cgf = ci << 7;
    __syncthreads();
    {
      const int c = tid & 127;
      const int db = tid >> 7;
#pragma unroll 8
      for (int k = 0; k < 64; ++k) {
        const int d = db + (k << 1);
        Ct[toff(c, d)] = Cb[(size_t)d * 2048 + cgf + c];
      }
      if (tid < 128) {
        const int cc = cgf + tid;
        s0L[tid] = Cmask[b * 2048 + cc] ? sub0[b * 2048 + cc] : -1e30f;
      }
    }
    __syncthreads();
    float acc[4][4];
#pragma unroll
    for (int i = 0; i < 4; ++i)
#pragma unroll
      for (int j = 0; j < 4; ++j) acc[i][j] = 0.f;
#pragma unroll 4
    for (int dc = 0; dc < 32; ++dc) {
      float4 qv[4];
#pragma unroll
      for (int j = 0; j < 4; ++j) qv[j] = *(const float4*)&Qw[toff4(q0 + j, dc)];
#pragma unroll
      for (int i = 0; i < 4; ++i) {
        const float4 cvv = *(const float4*)&Ct[toff4(c0 + i, dc)];
#pragma unroll
        for (int j = 0; j < 4; ++j)
          acc[i][j] += cvv.x * qv[j].x + cvv.y * qv[j].y + cvv.z * qv[j].z + cvv.w * qv[j].w;
      }
    }
#pragma unroll
    for (int i = 0; i < 4; ++i) {
      const float s0v = s0L[c0 + i];
#pragma unroll
      for (int j = 0; j < 4; ++j)
        eL[(c0 + i) * 33 + q0 + j] = __expf(acc[i][j] + s0v + s1L[q0 + j]);
    }
    __syncthreads();
#pragma unroll 4
    for (int c = 0; c < 128; ++c) {
      const float ev0 = eL[c * 33 + q0t];
      const float ev1 = eL[c * 33 + q0t + 1];
      if (dgrp == 0) { l2a0 += ev0; l2a1 += ev1; }
      const int sw = (c >> 2) & 7;
      const float4 ca = *(const float4*)&Ct[c * 128 + ((((dgrp << 1)) ^ sw) << 2)];
      const float4 cb2 = *(const float4*)&Ct[c * 128 + ((((dgrp << 1) | 1) ^ sw) << 2)];
      Tacc[0][0] += ev0 * ca.x; Tacc[0][1] += ev0 * ca.y;
      Tacc[0][2] += ev0 * ca.z; Tacc[0][3] += ev0 * ca.w;
      Tacc[0][4] += ev0 * cb2.x; Tacc[0][5] += ev0 * cb2.y;
      Tacc[0][6] += ev0 * cb2.z; Tacc[0][7] += ev0 * cb2.w;
      Tacc[1][0] += ev1 * ca.x; Tacc[1][1] += ev1 * ca.y;
      Tacc[1][2] += ev1 * ca.z; Tacc[1][3] += ev1 * ca.w;
      Tacc[1][4] += ev1 * cb2.x; Tacc[1][5] += ev1 * cb2.y;
      Tacc[1][6] += ev1 * cb2.z; Tacc[1][7] += ev1 * cb2.w;
    }
  }
  if (dgrp == 0) { l2L[q0t] = l2a0; l2L[q0t + 1] = l2a1; }
  __syncthreads();
  {
    const float inv0 = 1.f / l2L[q0t];
    const float inv1 = 1.f / l2L[q0t + 1];
    const size_t tb = ((size_t)b * 256 + q0g + q0t) * 128 + d0;
    float4 wv;
    wv.x = Tacc[0][0] * inv0; wv.y = Tacc[0][1] * inv0; wv.z = Tacc[0][2] * inv0; wv.w = Tacc[0][3] * inv0;
    *(float4*)&Tws[tb] = wv;
    wv.x = Tacc[0][4] * inv0; wv.y = Tacc[0][5] * inv0; wv.z = Tacc[0][6] * inv0; wv.w = Tacc[0][7] * inv0;
    *(float4*)&Tws[tb + 4] = wv;
    wv.x = Tacc[1][0] * inv1; wv.y = Tacc[1][1] * inv1; wv.z = Tacc[1][2] * inv1; wv.w = Tacc[1][3] * inv1;
    *(float4*)&Tws[tb + 128] = wv;
    wv.x = Tacc[1][4] * inv1; wv.y = Tacc[1][5] * inv1; wv.z = Tacc[1][6] * inv1; wv.w = Tacc[1][7] * inv1;
    *(float4*)&Tws[tb + 132] = wv;
  }
}

#define FB2_LDS_FLOATS (8192 + 8192 + 17408 + 256 + 64 + 64 + 256 + 128)

__global__ void __launch_bounds__(256, 1) fb_k2(
    const float* __restrict__ C, const float* __restrict__ Q,
    const int* __restrict__ Qmask, const float* __restrict__ w4mlu,
    const float* __restrict__ sub0, const float* __restrict__ sub1,
    const float* __restrict__ Tws, float* __restrict__ out) {
  extern __shared__ float lds[];
  float* Ct = lds;
  float* St = Ct + 8192;
  float* P = St + 8192;
  float* redL = P + 17408;
  float* l1L = redL + 256;
  float* s0L = l1L + 64;
  float* s1L = s0L + 64;
  float* w4L = s1L + 256;

  const int tid = threadIdx.x;
  const int b = blockIdx.x >> 5;
  const int c0g = (blockIdx.x & 31) << 6;
  const float* Cb = C + (size_t)b * (128 * (size_t)2048);
  const float* Qb = Q + (size_t)b * (128 * 256);

  s1L[tid] = sub1[b * 256 + tid] + (Qmask[b * 256 + tid] ? 0.f : -1e30f);
  if (tid < 64) s0L[tid] = sub0[b * 2048 + c0g + tid];
  if (tid >= 128 && tid < 256) w4L[tid - 128] = w4mlu[tid - 128];
  {
    const int c = tid & 63;
    const int db = tid >> 6;
#pragma unroll 8
    for (int k = 0; k < 32; ++k) {
      const int d = db + (k << 2);
      Ct[toff(c, d)] = Cb[(size_t)d * 2048 + c0g + c];
    }
  }
  __syncthreads();

  const int i0 = tid & 15, j0 = tid >> 4;
  const int c0 = i0 << 2, q0 = j0 << 2;
  const int dg = j0, d0 = j0 << 3;

  for (int qtc = 0; qtc < 4; ++qtc) {
    {
      const int q = tid & 63;
      const int db = tid >> 6;
#pragma unroll 8
      for (int k = 0; k < 32; ++k) {
        const int d = db + (k << 2);
        St[toff(q, d)] = Qb[d * 256 + (qtc << 6) + q] * w4L[d];
      }
    }
    __syncthreads();
    float acc[4][4];
#pragma unroll
    for (int i = 0; i < 4; ++i)
#pragma unroll
      for (int j = 0; j < 4; ++j) acc[i][j] = 0.f;
#pragma unroll 4
    for (int dc = 0; dc < 32; ++dc) {
      float4 qv[4];
#pragma unroll
      for (int j = 0; j < 4; ++j) qv[j] = *(const float4*)&St[toff4(q0 + j, dc)];
#pragma unroll
      for (int i = 0; i < 4; ++i) {
        const float4 cvv = *(const float4*)&Ct[toff4(c0 + i, dc)];
#pragma unroll
        for (int j = 0; j < 4; ++j)
          acc[i][j] += cvv.x * qv[j].x + cvv.y * qv[j].y + cvv.z * qv[j].z + cvv.w * qv[j].w;
      }
    }
#pragma unroll
    for (int j = 0; j < 4; ++j) {
      const int qq = (qtc << 6) + q0 + j;
      const float s1v = s1L[qq];
      float4 pv;
      pv.x = __expf(acc[0][j] + s0L[c0 + 0] + s1v);
      pv.y = __expf(acc[1][j] + s0L[c0 + 1] + s1v);
      pv.z = __expf(acc[2][j] + s0L[c0 + 2] + s1v);
      pv.w = __expf(acc[3][j] + s0L[c0 + 3] + s1v);
      *(float4*)&P[qq * 68 + c0] = pv;
    }
    __syncthreads();
  }
  {
    const int c = tid & 63, g = tid >> 6;
    float s = 0.f;
#pragma unroll 8
    for (int q = 0; q < 64; ++q) s += P[((g << 6) + q) * 68 + c];
    redL[tid] = s;
  }
  __syncthreads();
  if (tid < 64) l1L[tid] = 1.f / (redL[tid] + redL[64 + tid] + redL[128 + tid] + redL[192 + tid]);

  float accA[4][8];
#pragma unroll
  for (int i = 0; i < 4; ++i)
#pragma unroll
    for (int e = 0; e < 8; ++e) accA[i][e] = 0.f;
  for (int qtc = 0; qtc < 4; ++qtc) {
    __syncthreads();
    {
      const int q = tid & 63;
      const int db = tid >> 6;
#pragma unroll 8
      for (int k = 0; k < 32; ++k) {
        const int d = db + (k << 2);
        St[toff(q, d)] = Qb[d * 256 + (qtc << 6) + q];
      }
    }
    __syncthreads();
#pragma unroll 2
    for (int q = 0; q < 64; ++q) {
      const int qq = (qtc << 6) + q;
      const float4 pv = *(const float4*)&P[qq * 68 + c0];
      const int sw = (q >> 2) & 7;
      const float4 qa = *(const float4*)&St[q * 128 + ((((dg << 1)) ^ sw) << 2)];
      const float4 qb2 = *(const float4*)&St[q * 128 + ((((dg << 1) | 1) ^ sw) << 2)];
      const float pf[4] = {pv.x, pv.y, pv.z, pv.w};
      const float qf[8] = {qa.x, qa.y, qa.z, qa.w, qb2.x, qb2.y, qb2.z, qb2.w};
#pragma unroll
      for (int i = 0; i < 4; ++i)
#pragma unroll
        for (int e = 0; e < 8; ++e) accA[i][e] += pf[i] * qf[e];
    }
  }
  float accB[4][8];
#pragma unroll
  for (int i = 0; i < 4; ++i)
#pragma unroll
    for (int e = 0; e < 8; ++e) accB[i][e] = 0.f;
  for (int qtc = 0; qtc < 4; ++qtc) {
    __syncthreads();
    {
      const int dc = tid & 31;
      const int q0r = tid >> 5;
#pragma unroll
      for (int k = 0; k < 8; ++k) {
        const int q = q0r + (k << 3);
        const float4 tv = *(const float4*)&Tws[((size_t)b * 256 + (qtc << 6) + q) * 128 + (dc << 2)];
        *(float4*)&St[q * 128 + ((dc ^ ((q >> 2) & 7)) << 2)] = tv;
      }
    }
    __syncthreads();
#pragma unroll 2
    for (int q = 0; q < 64; ++q) {
      const int qq = (qtc << 6) + q;
      const float4 pv = *(const float4*)&P[qq * 68 + c0];
      const int sw = (q >> 2) & 7;
      const float4 qa = *(const float4*)&St[q * 128 + ((((dg << 1)) ^ sw) << 2)];
      const float4 qb2 = *(const float4*)&St[q * 128 + ((((dg << 1) | 1) ^ sw) << 2)];
      const float pf[4] = {pv.x, pv.y, pv.z, pv.w};
      const float qf[8] = {qa.x, qa.y, qa.z, qa.w, qb2.x, qb2.y, qb2.z, qb2.w};
#pragma unroll
      for (int i = 0; i < 4; ++i)
#pragma unroll
        for (int e = 0; e < 8; ++e) accB[i][e] += pf[i] * qf[e];
    }
  }
  __syncthreads();
  {
    float* Al = St;
    float* Bl = P;
#pragma unroll
    for (int i = 0; i < 4; ++i) {
      const float inv = l1L[c0 + i];
#pragma unroll
      for (int e = 0; e < 8; ++e) {
        Al[(d0 + e) * 64 + c0 + i] = accA[i][e] * inv;
        Bl[(d0 + e) * 64 + c0 + i] = accB[i][e] * inv;
      }
    }
  }
  __syncthreads();
  {
    const float* Al = St;
    const float* Bl = P;
    const int c = tid & 63;
    const int db = tid >> 6;
    const size_t ob = (size_t)b * (512 * 2048) + c0g + c;
#pragma unroll 4
    for (int k = 0; k < 32; ++k) {
      const int d = db + (k << 2);
      const float cvv = Ct[toff(c, d)];
      const float av = Al[d * 64 + c];
      const float bv = Bl[d * 64 + c];
      out[ob + (size_t)d * 2048] = cvv;
      out[ob + (size_t)(128 + d) * 2048] = av;
      out[ob + (size_t)(256 + d) * 2048] = cvv * av;
      out[ob + (size_t)(384 + d) * 2048] = cvv * bv;
    }
  }
}

// ------------------------------ launcher ------------------------------------
extern "C" void kernel_launch(void* const* d_in, const int* in_sizes, int n_in,
                              void* d_out, int out_size, void* d_ws, size_t ws_size,
                              hipStream_t stream) {
  (void)in_sizes; (void)n_in; (void)out_size;
  const float* C = (const float*)d_in[0];
  const float* Q = (const float*)d_in[1];
  const int* Cmask = (const int*)d_in[2];
  const int* Qmask = (const int*)d_in[3];
  const float* w4C = (const float*)d_in[4];
  const float* w4Q = (const float*)d_in[5];
  const float* w4mlu = (const float*)d_in[6];
  const float* bias = (const float*)d_in[7];
  float* out = (float*)d_out;
  char* wsb = (char*)d_ws;

  const size_t NEED_FULL = 73990144;
  const size_t NEED_HALF = 39518208;

  if (ws_size >= NEED_FULL) {
    u16* Ctb = (u16*)(wsb + 0);
    u16* Cdb = (u16*)(wsb + 16777216);
    u16* Qwb = (u16*)(wsb + 33554432);
    u16* Qdb = (u16*)(wsb + 35651584);
    u16* Tdq = (u16*)(wsb + 37748736);
    u16* Praw = (u16*)(wsb + 39845888);
    float* s0r = (float*)(wsb + 73400320);
    float* s0m = (float*)(wsb + 73662464);
    float* s1r = (float*)(wsb + 73924608);
    float* s1m = (float*)(wsb + 73957376);

    prepQ<<<32, 512, 0, stream>>>(Q, Qmask, w4Q, w4mlu, Qwb, Qdb, s1r, s1m);
    prepC<<<256, 512, 0, stream>>>(C, Cmask, w4C, bias, Ctb, Cdb, s0r, s0m, 0, 5);
    k1<<<512, 512, 0, stream>>>(Ctb, Cdb, Qwb, s0r, s0m, s1r, s1m, Tdq, Praw, 0, 5);
    k2<<<1024, 512, 0, stream>>>(C, Qdb, Tdq, Praw, out, 0, 5);
  } else if (ws_size >= NEED_HALF) {
    u16* Ctb = (u16*)(wsb + 0);
    u16* Cdb = (u16*)(wsb + 8388608);
    u16* Qwb = (u16*)(wsb + 16777216);
    u16* Qdb = (u16*)(wsb + 18874368);
    u16* Tdq = (u16*)(wsb + 20971520);
    u16* Praw = (u16*)(wsb + 22020096);
    float* s0r = (float*)(wsb + 38928384);
    float* s0m = (float*)(wsb + 39190528);
    float* s1r = (float*)(wsb + 39452672);
    float* s1m = (float*)(wsb + 39485440);

    prepQ<<<32, 512, 0, stream>>>(Q, Qmask, w4Q, w4mlu, Qwb, Qdb, s1r, s1m);
    for (int h = 0; h < 2; ++h) {
      prepC<<<128, 512, 0, stream>>>(C, Cmask, w4C, bias, Ctb, Cdb, s0r, s0m,
                                     16 * h, 4);
      k1<<<256, 512, 0, stream>>>(Ctb, Cdb, Qwb, s0r, s0m, s1r, s1m, Tdq, Praw,
                                  16 * h, 4);
      k2<<<512, 512, 0, stream>>>(C, Qdb, Tdq, Praw, out, 16 * h, 4);
    }
  } else {
    float* ws = (float*)d_ws;
    float* sub0 = ws;
    float* sub1 = ws + 65536;
    float* Tws = ws + 73728;
    (void)hipFuncSetAttribute(reinterpret_cast<const void*>(fb_k1),
                              hipFuncAttributeMaxDynamicSharedMemorySize,
                              (int)(FB1_LDS_FLOATS * sizeof(float)));
    (void)hipFuncSetAttribute(reinterpret_cast<const void*>(fb_k2),
                              hipFuncAttributeMaxDynamicSharedMemorySize,
                              (int)(FB2_LDS_FLOATS * sizeof(float)));
    fb_sub0<<<256, 256, 0, stream>>>(C, w4C, bias, sub0);
    fb_sub1<<<32, 256, 0, stream>>>(Q, w4Q, sub1);
    fb_k1<<<256, 256, FB1_LDS_FLOATS * sizeof(float), stream>>>(C, Q, Cmask, w4mlu,
                                                                sub0, sub1, Tws);
    fb_k2<<<1024, 256, FB2_LDS_FLOATS * sizeof(float), stream>>>(C, Q, Qmask, w4mlu,
                                                                 sub0, sub1, Tws, out);
  }
}